// Round 4
// baseline (235.673 us; speedup 1.0000x reference)
//
#include <hip/hip_runtime.h>

// ExtractPatchesPositionLayer — R4: dbuf-pipelined LDS staging.
// out[b,i,j,c] = bilinear(img[b], y=i+32+oy[b,c], x=j+32+ox[b,c]).
// Weights constant per (b,c) (integer row offset folds into floor); taps
// always in-bounds (|shift|<=20, c0=32) -> reference OOB path never taken.
//
// R2/R3 both ~67us kernel regardless of compute cost -> limiter is the
// stage -> __syncthreads (s_waitcnt vmcnt(0) drain) -> compute chain per
// block generation (16/CU), staging latency never hidden. R4: persistent
// blocks, 8 half-batch items each, double-buffered LDS (2x76 rows = 76KiB,
// 2 blocks/CU), raw s_barrier + counted s_waitcnt vmcnt(5): stage(t+1)
// stays in flight across compute(t). (Guide §5 "minimum 2-phase" schedule.)

constexpr int Mdim   = 128;  // padded image side
constexpr int Npatch = 64;   // output patch side
constexpr int Cc     = 4;    // channels
constexpr int C0     = 32;   // (M - N) / 2
constexpr int SROWS  = 76;   // staged rows per buffer (covers span<=74)
constexpr int CHUNKS = (SROWS * Mdim) / 256;  // 38 x 1KiB staging chunks
constexpr int CPW    = 5;    // chunks per wave, padded (dup-clamped) -> uniform vmcnt
constexpr int ITEMS  = 8;    // half-batch work items per block

__global__ __launch_bounds__(512, 4) void extract_patches_kernel(
    const float* __restrict__ img,   // [B, M, M]
    const float* __restrict__ pos,   // [B, 1, 2, C]: axis0=x, axis1=y
    float* __restrict__ out)         // [B, N, N, C]
{
    __shared__ float lds[2][SROWS * Mdim];   // 77824 B -> 2 blocks/CU

    const int tid  = threadIdx.x;
    const int lane = tid & 63;
    const int wave = tid >> 6;               // also the 4-row strip index

    const int item0 = blockIdx.x * ITEMS;    // first half-batch item
    const int b0    = item0 >> 1;            // first batch (4 per block)

    // ---- Preload this block's 4 batches' positions (broadcast -> regs) ----
    float oxv[4][Cc], oyv[4][Cc];
#pragma unroll
    for (int q = 0; q < 4; ++q) {
        const float* pb = pos + (size_t)(b0 + q) * (2 * Cc);
#pragma unroll
        for (int c = 0; c < Cc; ++c) { oxv[q][c] = pb[c]; oyv[q][c] = pb[Cc + c]; }
    }

    int   iyC[Cc], ixC[Cc], r0C; float wC[Cc][4];   // current item consts
    int   iyN[Cc], ixN[Cc], r0N; float wN[Cc][4];   // next item consts

    auto make_consts = [&](int t, int* iy, int* ix, float (*w)[4], int& r0) {
        const int q = (t >> 1) & 3, h = t & 1;
        int mn = Mdim;
#pragma unroll
        for (int c = 0; c < Cc; ++c) {
            const float ox = oxv[q][c], oy = oyv[q][c];
            const float fx = floorf(ox), fy = floorf(oy);
            const float wx = ox - fx,   wy = oy - fy;
            ix[c] = C0 + (int)fx;        // in [12, 51]
            iy[c] = C0 + (int)fy;        // in [12, 51]
            w[c][0] = (1.f - wy) * (1.f - wx);
            w[c][1] = (1.f - wy) * wx;
            w[c][2] = wy * (1.f - wx);
            w[c][3] = wy * wx;
            mn = min(mn, iy[c]);
        }
        // window [r0, r0+75] covers needed rows [mn+32h, mn+32h+72],
        // clamped in-bounds (<=127). Needed-min stays >= r0 when clamped.
        r0 = min(mn + 32 * h, Mdim - SROWS);
    };

    auto stage = [&](int t, int r0) {
        const int b = (item0 + t) >> 1;
        const float* src = img + (size_t)b * (Mdim * Mdim) + r0 * Mdim;
        float* dst = &lds[t & 1][0];
#pragma unroll
        for (int k = 0; k < CPW; ++k) {
            // dup-clamp last chunks: waves 5,6,7 re-stage chunk 37 with
            // identical data (benign) -> uniform 5 instrs/wave for vmcnt.
            const int wc = min(wave + 8 * k, CHUNKS - 1);
            __builtin_amdgcn_global_load_lds(
                (const __attribute__((address_space(1))) void*)(src + wc * 256 + lane * 4),
                (__attribute__((address_space(3))) void*)(dst + wc * 256),
                16, 0, 0);
        }
    };

    auto compute = [&](int t, const int* iy, const int* ix, const float (*w)[4], int r0) {
        const int b = (item0 + t) >> 1, h = t & 1;
        const float* buf = &lds[t & 1][0];
        const int li0 = wave * 4;            // 4 consecutive output rows
        const int j   = lane;                // column 0..63
        int a[Cc]; float p0[Cc], p1[Cc];
#pragma unroll
        for (int c = 0; c < Cc; ++c) {
            a[c]  = (iy[c] + 32 * h + li0 - r0) * Mdim + ix[c] + j;
            p0[c] = buf[a[c]];
            p1[c] = buf[a[c] + 1];           // adjacent pair -> ds_read2_b32
        }
        float* obase = out + (((size_t)b * Npatch + 32 * h + li0) * Npatch + j) * Cc;
#pragma unroll
        for (int k = 0; k < 4; ++k) {
            float4 o; float* res = reinterpret_cast<float*>(&o);
#pragma unroll
            for (int c = 0; c < Cc; ++c) {
                a[c] += Mdim;                // rolling row reuse: 2 dwords/output
                const float n0 = buf[a[c]], n1 = buf[a[c] + 1];
                res[c] = w[c][0] * p0[c] + w[c][1] * p1[c] + w[c][2] * n0 + w[c][3] * n1;
                p0[c] = n0; p1[c] = n1;
            }
            *reinterpret_cast<float4*>(obase + (size_t)k * Npatch * Cc) = o;
        }
    };

    // ---- prologue ----
    make_consts(0, iyC, ixC, wC, r0C);
    stage(0, r0C);

    // ---- 2-phase pipelined main loop ----
#pragma unroll
    for (int t = 0; t < ITEMS; ++t) {
        if (t + 1 < ITEMS) {
            make_consts(t + 1, iyN, ixN, wN, r0N);
            stage(t + 1, r0N);               // into buf[(t+1)&1]
            // wait until only stage(t+1)'s 5 remain -> stage(t) + all older
            // (prologue pos loads, prior stores) complete. Never vmcnt(0).
            asm volatile("s_waitcnt vmcnt(5)" ::: "memory");
        } else {
            asm volatile("s_waitcnt vmcnt(0)" ::: "memory");
        }
        __builtin_amdgcn_s_barrier();
        asm volatile("" ::: "memory");       // keep ds_reads below barrier

        compute(t, iyC, ixC, wC, r0C);

        asm volatile("" ::: "memory");       // keep ds_reads above barrier
        __builtin_amdgcn_s_barrier();        // buf[t&1] free for stage(t+2)

        if (t + 1 < ITEMS) {
#pragma unroll
            for (int c = 0; c < Cc; ++c) {
                iyC[c] = iyN[c]; ixC[c] = ixN[c];
#pragma unroll
                for (int z = 0; z < 4; ++z) wC[c][z] = wN[c][z];
            }
            r0C = r0N;
        }
    }
}

extern "C" void kernel_launch(void* const* d_in, const int* in_sizes, int n_in,
                              void* d_out, int out_size, void* d_ws, size_t ws_size,
                              hipStream_t stream) {
    const float* img = (const float*)d_in[0];  // padded_obj [B,128,128,1] f32
    const float* pos = (const float*)d_in[1];  // positions  [B,1,2,4]   f32
    float* out = (float*)d_out;                // [B,64,64,4] f32

    const int B = in_sizes[0] / (Mdim * Mdim); // 2048
    const int nblocks = (2 * B) / ITEMS;       // 512 persistent-ish blocks
    extract_patches_kernel<<<dim3(nblocks), dim3(512), 0, stream>>>(img, pos, out);
}